// Round 1
// baseline (67.176 us; speedup 1.0000x reference)
//
#include <hip/hip_runtime.h>

// Light-cone-reduced circuit: entangled cluster = 64 amps = ONE wavefront.
// This round: code-size minimization round 2 (kernel runs icache-cold every
// replay; serial I$ miss fetch ~ static bytes). Changes vs prev:
//  - closed-form SU(2) build: M = Rx*Ry*Rz => M0=u*w, M2=v*w,
//    M1=-conj(M2), M3=conj(M0). Kills both mat2mul's (~110 instrs).
//  - initial spinors via the SAME path (tx=0): Rz*Ry|0> = (M0, conj(M2)),
//    built by lanes 10-13; kills 4 inlined spin() blocks.
//  - one float4 LDS entry per matrix (single ds_read_b128 in the gate loop).
//  - #pragma unroll 1 pins the gate loop rolled (icache).

struct cplx { float x, y; };
__device__ __forceinline__ cplx cmul(cplx a, cplx b){ return {a.x*b.x - a.y*b.y, a.x*b.y + a.y*b.x}; }
__device__ __forceinline__ cplx cadd(cplx a, cplx b){ return {a.x+b.x, a.y+b.y}; }

// op encoding: bit0 = kind (0=rot, 1=cnot); bits[4:1] = target bit;
// bits[8:5] = ctrl bit (15 = none); bits[12:9] = matrix index (rot only).
#define OPR(b,m,c) (unsigned short)(((m)<<9)|((c)<<5)|((b)<<1))
#define OPC(c,t)   (unsigned short)(((c)<<5)|((t)<<1)|1)
// matrices: 0 CRx-angle 1 CRy1 2 CRz 3 CRy2 4 S0e 5 S0n 6 S0a 7 S1a 8 S1n 9 S1x
#define PASS(eb,nb) \
  OPR(1,0,nb), OPR(1,1,eb), OPR(0,2,nb), OPR(0,3,eb), \
  OPR(eb,4,15), OPR(nb,5,15), OPR(1,6,15), \
  OPC(eb,nb), OPC(nb,1), OPC(1,eb), \
  OPR(1,7,15), OPR(nb,8,15), OPR(0,9,15), \
  OPC(1,nb), OPC(nb,0), OPC(0,1)

__device__ const unsigned short OPS[32] = { PASS(5,3), PASS(4,2) };

__global__ __launch_bounds__(64)
void qlightcone(const float* __restrict__ inf, const float* __restrict__ inits,
                const float* __restrict__ s0p, const float* __restrict__ s1p,
                float* __restrict__ out)
{
  // M[14] = {M0.x, M0.y, M2.x, M2.y}; M1 = -conj(M2), M3 = conj(M0).
  // rows 0-9: gate matrices; rows 10-13: initial spinors (tx=0 path):
  //   spin(bit) = bit ? conj(M2) : M0.
  __shared__ float4 Mlds[14];
  const int lane = threadIdx.x;

  {
    const int ml = (lane < 14) ? lane : 4;
    float tx = 0.f, ty = 0.f, tz = 0.f;
    if (ml < 4){
      const float a = inits[ml];
      tx = (ml == 0) ? a : 0.f;
      ty = (ml & 1)  ? a : 0.f;   // ml==1 || ml==3
      tz = (ml == 2) ? a : 0.f;
    } else if (ml < 10){
      const float* pp = (ml < 7) ? s0p + 3*(ml - 4) : s1p + 3*(ml - 7);
      tz = pp[0]; ty = pp[1]; tx = pp[2];   // reference applies Rz, Ry, Rx
    } else {
      // spinors: rows 10..13 <-> lane bits b5,b4,b3,b2; (ty,tz) pairs at
      // inf[{0,2,18,20}]
      const int q = ml - 10;
      const int idx = q*2 + ((q >= 2) ? 14 : 0);
      ty = inf[idx]; tz = inf[idx + 1];
    }
    const float sx = __sinf(0.5f*tx), cx = __cosf(0.5f*tx);
    const float sy = __sinf(0.5f*ty), cy = __cosf(0.5f*ty);
    const float sz = __sinf(0.5f*tz), cz = __cosf(0.5f*tz);
    // M = Rx*Ry*Rz:  M0 = u*w, M2 = v*w
    const cplx u = { cx*cy, -sx*sy };
    const cplx v = { cx*sy, -sx*cy };
    const cplx w = { cz, -sz };
    const cplx a = cmul(u, w), b = cmul(v, w);
    if (lane < 14) Mlds[lane] = make_float4(a.x, a.y, b.x, b.y);
  }
  __syncthreads();

  // ---- initial product state from the 4 spinors (rows 10-13); anc b1,b0 = |0>
  cplx amp = {1.f, 0.f};
  #pragma unroll 1
  for (int q = 0; q < 4; ++q){
    const float4 mm = Mlds[10 + q];
    const int bit = (lane >> (5 - q)) & 1;
    const cplx s = bit ? cplx{mm.z, -mm.w} : cplx{mm.x, mm.y};
    amp = cmul(amp, s);
  }
  if (lane & 3) amp = {0.f, 0.f};

  // ---- gate loop (scalar-uniform decode; per-lane work is shfl + few VALU)
  #pragma unroll 1
  for (int i = 0; i < 32; ++i){
    const int op   = OPS[i];
    const int b    = (op >> 1) & 15;
    const int c    = (op >> 5) & 15;
    const cplx p   = { __shfl_xor(amp.x, 1 << b), __shfl_xor(amp.y, 1 << b) };
    const bool cok = (c == 15) || ((lane >> c) & 1);
    if (op & 1){                       // CNOT: swap pair where ctrl set
      if (cok) amp = p;
    } else {                           // controlled/plain 2x2 rotation
      const int m = (op >> 9) & 15;
      const float4 mm = Mlds[m];
      const bool hi = (lane >> b) & 1;
      const cplx lo_ = hi ? p : amp, hi_ = hi ? amp : p;
      // row of M for this lane: lo: (M0, M1=-conj(M2)); hi: (M2, M3=conj(M0))
      const cplx A = hi ? cplx{mm.z, mm.w} : cplx{mm.x, mm.y};
      const cplx B = hi ? cplx{mm.x, -mm.y} : cplx{-mm.z, mm.w};
      const cplx na = cadd(cmul(A, lo_), cmul(B, hi_));
      if (cok) amp = na;
    }
  }

  // ---- <Z> on measured bit b2
  float s = amp.x*amp.x + amp.y*amp.y;
  if ((lane >> 2) & 1) s = -s;
  #pragma unroll
  for (int off = 32; off > 0; off >>= 1) s += __shfl_down(s, off);
  if (lane == 0) out[0] = s;
}

extern "C" void kernel_launch(void* const* d_in, const int* in_sizes, int n_in,
                              void* d_out, int out_size, void* d_ws, size_t ws_size,
                              hipStream_t stream) {
  const float* inf   = (const float*)d_in[0];
  const float* inits = (const float*)d_in[1];
  const float* s0p   = (const float*)d_in[2];
  const float* s1p   = (const float*)d_in[3];
  // d_in[4] (update_params) provably cannot affect the output: unitary outside
  // the light cone (verified absmax 0.0 against the JAX reference).
  float* out = (float*)d_out;

  qlightcone<<<dim3(1), dim3(64), 0, stream>>>(inf, inits, s0p, s1p, out);
}

// Round 2
// 61.741 us; speedup vs baseline: 1.0880x; 1.0880x over previous
//
#include <hip/hip_runtime.h>

// Light-cone-reduced circuit: entangled cluster = 64 amps = ONE wavefront,
// lane bits [b5..b0] = [edge0, edge1, vert1, vert2(measured), anc1, anc2].
//
// Round-2 shape theory: single-wave kernel => serial DYNAMIC instruction count
// dominates (no TLP to hide anything); straight-line code streams through the
// I$ prefetcher, rolled loops pay per-iteration decode. So: FULL unroll with a
// constexpr op table (every mask/offset an immediate), closed-form SU(2) build
// (no mat2mul), spinors through the same build path, and the six lane-bit
// predicates hoisted once (each gate's hi/cok select reuses a cached mask).

struct cplx { float x, y; };
__device__ __forceinline__ cplx cmul(cplx a, cplx b){ return {a.x*b.x - a.y*b.y, a.x*b.y + a.y*b.x}; }

// op encoding: bit0 = kind (0=rot, 1=cnot); bits[4:1] = target bit;
// bits[8:5] = ctrl bit (15 = none); bits[12:9] = matrix index (rot only).
#define OPR(b,m,c) (unsigned short)(((m)<<9)|((c)<<5)|((b)<<1))
#define OPC(c,t)   (unsigned short)(((c)<<5)|((t)<<1)|1)
// matrices: 0 CRx-angle 1 CRy1 2 CRz 3 CRy2 4 S0e 5 S0n 6 S0a 7 S1a 8 S1n 9 S1x
#define PASS(eb,nb) \
  OPR(1,0,nb), OPR(1,1,eb), OPR(0,2,nb), OPR(0,3,eb), \
  OPR(eb,4,15), OPR(nb,5,15), OPR(1,6,15), \
  OPC(eb,nb), OPC(nb,1), OPC(1,eb), \
  OPR(1,7,15), OPR(nb,8,15), OPR(0,9,15), \
  OPC(1,nb), OPC(nb,0), OPC(0,1)

constexpr unsigned short OPS[32] = { PASS(5,3), PASS(4,2) };

__global__ __launch_bounds__(64)
void qlightcone(const float* __restrict__ inf, const float* __restrict__ inits,
                const float* __restrict__ s0p, const float* __restrict__ s1p,
                float* __restrict__ out)
{
  // Mlds[i] = {M0.x, M0.y, M2.x, M2.y}; M1 = -conj(M2), M3 = conj(M0).
  // rows 0-9: gate matrices; rows 10-13: initial spinors (tx=0 path):
  //   spin(bit) = bit ? conj(M2) : M0.
  __shared__ float4 Mlds[14];
  const int lane = threadIdx.x;

  {
    const int ml = (lane < 14) ? lane : 4;
    float tx = 0.f, ty = 0.f, tz = 0.f;
    if (ml < 4){
      const float a = inits[ml];
      tx = (ml == 0) ? a : 0.f;
      ty = (ml & 1)  ? a : 0.f;   // ml==1 || ml==3
      tz = (ml == 2) ? a : 0.f;
    } else if (ml < 10){
      const float* pp = (ml < 7) ? s0p + 3*(ml - 4) : s1p + 3*(ml - 7);
      tz = pp[0]; ty = pp[1]; tx = pp[2];   // reference applies Rz, Ry, Rx
    } else {
      // spinors: rows 10..13 <-> lane bits b5,b4,b3,b2; (ty,tz) at inf[{0,2,18,20}]
      const int q = ml - 10;
      const int idx = q*2 + ((q >= 2) ? 14 : 0);
      ty = inf[idx]; tz = inf[idx + 1];
    }
    const float sx = __sinf(0.5f*tx), cx = __cosf(0.5f*tx);
    const float sy = __sinf(0.5f*ty), cy = __cosf(0.5f*ty);
    const float sz = __sinf(0.5f*tz), cz = __cosf(0.5f*tz);
    // M = Rx*Ry*Rz:  M0 = u*w, M2 = v*w
    const cplx u = { cx*cy, -sx*sy };
    const cplx v = { cx*sy, -sx*cy };
    const cplx w = { cz, -sz };
    const cplx a = cmul(u, w), b = cmul(v, w);
    if (lane < 14) Mlds[lane] = make_float4(a.x, a.y, b.x, b.y);
  }
  __syncthreads();

  // ---- hoist the six lane-bit predicates (each becomes one cached cmp mask)
  bool bt[6];
  #pragma unroll
  for (int k = 0; k < 6; ++k) bt[k] = (lane >> k) & 1;

  // ---- initial product state from the 4 spinors (rows 10-13); anc b1,b0 = |0>
  cplx amp = {1.f, 0.f};
  #pragma unroll
  for (int q = 0; q < 4; ++q){
    const float4 mm = Mlds[10 + q];
    const cplx s = bt[5 - q] ? cplx{mm.z, -mm.w} : cplx{mm.x, mm.y};
    amp = cmul(amp, s);
  }
  if (lane & 3) amp = {0.f, 0.f};

  // ---- gate sequence, fully unrolled: every mask/offset folds to an immediate
  #pragma unroll
  for (int i = 0; i < 32; ++i){
    const int op   = OPS[i];
    const int b    = (op >> 1) & 15;
    const int c    = (op >> 5) & 15;
    const cplx p   = { __shfl_xor(amp.x, 1 << b), __shfl_xor(amp.y, 1 << b) };
    const bool cok = (c == 15) || bt[c];
    if (op & 1){                       // CNOT: swap pair where ctrl set
      if (cok) amp = p;
    } else {                           // controlled/plain 2x2 rotation
      const int m = (op >> 9) & 15;
      const float4 mm = Mlds[m];
      const bool hi = bt[b];
      const cplx lo_ = hi ? p : amp, hi_ = hi ? amp : p;
      // row of M for this lane: lo: (M0, M1=-conj(M2)); hi: (M2, M3=conj(M0))
      const cplx A = hi ? cplx{mm.z, mm.w}   : cplx{mm.x, mm.y};
      const cplx B = hi ? cplx{mm.x, -mm.y}  : cplx{-mm.z, mm.w};
      cplx na;
      na.x = A.x*lo_.x - A.y*lo_.y + B.x*hi_.x - B.y*hi_.y;
      na.y = A.x*lo_.y + A.y*lo_.x + B.x*hi_.y + B.y*hi_.x;
      if (cok) amp = na;
    }
  }

  // ---- <Z> on measured bit b2
  float s = amp.x*amp.x + amp.y*amp.y;
  if (bt[2]) s = -s;
  #pragma unroll
  for (int off = 32; off > 0; off >>= 1) s += __shfl_down(s, off);
  if (lane == 0) out[0] = s;
}

extern "C" void kernel_launch(void* const* d_in, const int* in_sizes, int n_in,
                              void* d_out, int out_size, void* d_ws, size_t ws_size,
                              hipStream_t stream) {
  const float* inf   = (const float*)d_in[0];
  const float* inits = (const float*)d_in[1];
  const float* s0p   = (const float*)d_in[2];
  const float* s1p   = (const float*)d_in[3];
  // d_in[4] (update_params) provably cannot affect the output: unitary outside
  // the light cone (verified absmax 0.0 against the JAX reference).
  float* out = (float*)d_out;

  qlightcone<<<dim3(1), dim3(64), 0, stream>>>(inf, inits, s0p, s1p, out);
}